// Round 6
// baseline (1708.660 us; speedup 1.0000x reference)
//
#include <hip/hip_runtime.h>
#include <hip/hip_fp16.h>
#include <math.h>

// Problem constants (match reference)
constexpr int N_NODES = 65536;
constexpr int N_EDGES = 2097152;
constexpr int F_IN    = 128;
constexpr int H_DIM   = 256;
constexpr int O_DIM   = 128;
constexpr int N_GRAPH = 256;
constexpr int V_SIZE  = 1000;

// 256 buckets of 256 nodes (bucket = col>>8); 256 edge-blocks of 8192 edges.
constexpr int EPB  = 8192;
constexpr int NBLK = N_EDGES / EPB;   // 256
constexpr float FXP = 16777216.0f;    // 2^24
constexpr int CSR2_TOT = N_EDGES + N_NODES;   // edges + self-loops

typedef _Float16 half8 __attribute__((ext_vector_type(8)));
typedef float floatx4 __attribute__((ext_vector_type(4)));

// ---------------- init: pool=0, graph counts, cfW1 table, W2T fp16 ----------

__global__ void k_init(float* __restrict__ pool, const int* __restrict__ batch,
                       float* __restrict__ cntf, const float* __restrict__ cf,
                       const float* __restrict__ W1, __half* __restrict__ cfW1,
                       const float* __restrict__ W2, _Float16* __restrict__ W2T) {
    __shared__ float xs[8 * F_IN];    // 4 KB
    int i = blockIdx.x * blockDim.x + threadIdx.x;
    if (i < N_GRAPH * O_DIM) pool[i] = 0.0f;
    if (blockIdx.x == 0) {
        // batch_index sorted: per-graph counts via binary search, no atomics
        int g = threadIdx.x;
        int lo = 0, hi = N_NODES;
        while (lo < hi) { int m = (lo + hi) >> 1; if (batch[m] < g) lo = m + 1; else hi = m; }
        int start = lo;
        lo = 0; hi = N_NODES;
        while (lo < hi) { int m = (lo + hi) >> 1; if (batch[m] <= g) lo = m + 1; else hi = m; }
        cntf[g] = (float)(lo - start);
    }
    if (blockIdx.x < V_SIZE / 8) {    // 125 blocks compute the cfW1 table
        int rb = blockIdx.x * 8;
        int t  = threadIdx.x;
        #pragma unroll
        for (int p = 0; p < 4; ++p) {
            int idx = p * 256 + t;
            int r = idx >> 7, k = idx & 127;
            xs[idx] = cf[(size_t)(rb + r) * F_IN + k];
        }
        __syncthreads();
        float acc[8] = {};
        for (int k = 0; k < F_IN; ++k) {
            float w = W1[k * H_DIM + t];
            #pragma unroll
            for (int j = 0; j < 8; ++j) acc[j] += xs[j * F_IN + k] * w;
        }
        #pragma unroll
        for (int j = 0; j < 8; ++j)
            cfW1[(size_t)(rb + j) * H_DIM + t] = __float2half(acc[j]);
    }
    if (blockIdx.x >= 128) {          // 128 blocks: W2T transpose fp32->fp16
        int idx = (blockIdx.x - 128) * 256 + threadIdx.x;   // 0..32767
        int nn = idx >> 8, kk = idx & 255;
        W2T[idx] = (_Float16)W2[kk * O_DIM + nn];
    }
}

// ---------------- stage A: per-block bucket histogram (LDS) ----------------

__global__ void k_hist(const int* __restrict__ col, int* __restrict__ hist) {
    __shared__ int h[256];
    int t = threadIdx.x;
    h[t] = 0;
    __syncthreads();
    int base = blockIdx.x * EPB;
    #pragma unroll
    for (int i = 0; i < EPB / 256; ++i)
        atomicAdd(&h[col[base + i * 256 + t] >> 8], 1);
    __syncthreads();
    hist[t * NBLK + blockIdx.x] = h[t];   // bucket-major for the scan
}

// ---------------- scan (partial per-256-chunk + block sums) ----------------

__global__ void k_scan1(const int* __restrict__ in, int* __restrict__ out,
                        int* __restrict__ bsum) {
    __shared__ int s[256];
    int tid = threadIdx.x;
    int i = blockIdx.x * 256 + tid;
    int v = in[i];
    s[tid] = v;
    __syncthreads();
    for (int d = 1; d < 256; d <<= 1) {
        int t = (tid >= d) ? s[tid - d] : 0;
        __syncthreads();
        s[tid] += t;
        __syncthreads();
    }
    out[i] = s[tid] - v;
    if (tid == 255) bsum[blockIdx.x] = s[255];
}

__global__ void k_scan2(int* __restrict__ bsum) {
    __shared__ int s[256];
    int tid = threadIdx.x;
    int v = bsum[tid];
    s[tid] = v;
    __syncthreads();
    for (int d = 1; d < 256; d <<= 1) {
        int t = (tid >= d) ? s[tid - d] : 0;
        __syncthreads();
        s[tid] += t;
        __syncthreads();
    }
    bsum[tid] = s[tid] - v;
}

// ---------------- stage C: partition into int2 records ----------------------
// rec.x = src:16 | dst8:8 | vocab_hi:8 ; rec.y = vocab_lo:2<<16 | ew_fp16:16

__global__ void k_part(const int* __restrict__ row, const int* __restrict__ col,
                       const float* __restrict__ ew, const int* __restrict__ nidx,
                       const int* __restrict__ hoffs, const int* __restrict__ bsum,
                       int2* __restrict__ part) {
    __shared__ int cur[256];
    int t = threadIdx.x;
    cur[t] = hoffs[t * NBLK + blockIdx.x] + bsum[t];
    __syncthreads();
    int base = blockIdx.x * EPB;
    for (int i = 0; i < EPB / 256; ++i) {
        int e = base + i * 256 + t;
        int r = row[e], c = col[e];
        unsigned hw = (unsigned)__half_as_ushort(__float2half(ew[e]));
        int vb = nidx[r];
        int slot = atomicAdd(&cur[c >> 8], 1);
        int2 rec;
        rec.x = (r << 16) | ((c & 255) << 8) | (vb >> 2);
        rec.y = (int)(((unsigned)(vb & 3) << 16) | hw);
        part[slot] = rec;
    }
}

// ---------------- stage D1: per-bucket deg/dis + offs + slice offs2 ---------

__global__ void k_build1(const int* __restrict__ hoffs, const int* __restrict__ bsum,
                         const int2* __restrict__ part, float* __restrict__ dis,
                         int* __restrict__ offs, int* __restrict__ offs2) {
    __shared__ unsigned long long dc[256];
    __shared__ int sc[256];
    __shared__ int c4[4];
    int t = threadIdx.x;
    int bucket = blockIdx.x;
    dc[t] = 0ULL;
    if (t < 4) c4[t] = 0;
    __syncthreads();
    int start = hoffs[bucket * NBLK] + bsum[bucket];
    int end   = (bucket == 255) ? N_EDGES : (hoffs[(bucket + 1) * NBLK] + bsum[bucket + 1]);
    int l0 = 0, l1 = 0, l2 = 0, l3 = 0;
    for (int j = start + t; j < end; j += 256) {
        int2 rec = part[j];
        int dst = (rec.x >> 8) & 255;
        float w = __half2float(__ushort_as_half((unsigned short)(rec.y & 0xFFFF)));
        atomicAdd(&dc[dst], (1ULL << 40) |
                  (unsigned long long)(unsigned)(w * FXP + 0.5f));
        unsigned sl = ((unsigned)rec.x) >> 30;     // src>>14
        if (sl == 0) ++l0; else if (sl == 1) ++l1; else if (sl == 2) ++l2; else ++l3;
    }
    if (l0) atomicAdd(&c4[0], l0);
    if (l1) atomicAdd(&c4[1], l1);
    if (l2) atomicAdd(&c4[2], l2);
    if (l3) atomicAdd(&c4[3], l3);
    __syncthreads();
    unsigned long long v = dc[t];
    float deg = 1.0f + (float)(v & 0xFFFFFFFFFFULL) * (1.0f / FXP);   // self-loop +1
    dis[bucket * 256 + t] = 1.0f / sqrtf(deg);                        // deg >= 1
    if (t == 0) {
        int sb = bucket >> 6;
        int o = start + bucket * 256;       // bucket base in csr2 (incl. self slots)
        #pragma unroll
        for (int p = 0; p < 4; ++p) {
            offs2[bucket * 4 + p] = o;
            o += c4[p] + (p == sb ? 256 : 0);
        }
        if (bucket == 255) offs2[1024] = CSR2_TOT;
    }
    int cnt = (int)(v >> 40);
    sc[t] = cnt;
    __syncthreads();
    for (int d = 1; d < 256; d <<= 1) {
        int x = (t >= d) ? sc[t - d] : 0;
        __syncthreads();
        sc[t] += x;
        __syncthreads();
    }
    offs[bucket * 256 + t] = start + sc[t] - cnt;
    if (bucket == 255 && t == 255) offs[N_NODES] = N_EDGES;
}

// ---------------- stage D2: scatter to per-dst CSR (agg1) + sliced csr2 -----
// csr : x = src<<10 | vocab ; y = dis[src]*ew           (per-dst, for agg1)
// csr2: x = src<<8  | dst8  ; y = dis[src]*ew           (bucket+src-slice, agg2)
// self-loop recs reserved at the front of each bucket's home slice segment.

__global__ void k_build2(const int* __restrict__ hoffs, const int* __restrict__ bsum,
                         const int2* __restrict__ part, const float* __restrict__ dis,
                         const int* __restrict__ offs, const int* __restrict__ offs2,
                         int2* __restrict__ csr, int2* __restrict__ csr2) {
    __shared__ int cur[256];
    __shared__ int cur2[4];
    int t = threadIdx.x;
    int bucket = blockIdx.x;
    int sb = bucket >> 6;
    cur[t] = offs[bucket * 256 + t];
    if (t < 4) cur2[t] = offs2[bucket * 4 + t] + (t == sb ? 256 : 0);
    __syncthreads();
    // self-loop record for node bucket*256+t
    {
        int c = bucket * 256 + t;
        int2 r2;
        r2.x = (c << 8) | t;
        r2.y = __float_as_int(dis[c]);
        csr2[offs2[bucket * 4 + sb] + t] = r2;
    }
    int start = hoffs[bucket * NBLK] + bsum[bucket];
    int end   = (bucket == 255) ? N_EDGES : (hoffs[(bucket + 1) * NBLK] + bsum[bucket + 1]);
    for (int j = start + t; j < end; j += 256) {
        int2 rec = part[j];
        int dst = (rec.x >> 8) & 255;
        unsigned src = ((unsigned)rec.x) >> 16;
        int vb = ((rec.x & 255) << 2) | ((rec.y >> 16) & 3);
        float w = __half2float(__ushort_as_half((unsigned short)(rec.y & 0xFFFF)));
        float nm = dis[src] * w;
        int slot = atomicAdd(&cur[dst], 1);
        int2 e;
        e.x = (int)((src << 10) | (unsigned)vb);
        e.y = __float_as_int(nm);
        csr[slot] = e;
        int slice = (int)(src >> 14);
        int slot2 = atomicAdd(&cur2[slice], 1);
        int2 r2;
        r2.x = (int)((src << 8) | (unsigned)dst);
        r2.y = __float_as_int(nm);
        csr2[slot2] = r2;
    }
}

// 8-half fp16 row-fragment accumulate: e[k] += f32(v[k]) * n
__device__ __forceinline__ void acc8(float* e, int4 v, float n) {
    float2 f0 = __half22float2(*(__half2*)&v.x);
    float2 f1 = __half22float2(*(__half2*)&v.y);
    float2 f2 = __half22float2(*(__half2*)&v.z);
    float2 f3 = __half22float2(*(__half2*)&v.w);
    e[0] += f0.x * n; e[1] += f0.y * n;
    e[2] += f1.x * n; e[3] += f1.y * n;
    e[4] += f2.x * n; e[5] += f2.y * n;
    e[6] += f3.x * n; e[7] += f3.y * n;
}

// ---------------- fused layer-1 agg + GEMM2 (unchanged from R4) -------------

__global__ void __launch_bounds__(256) k_agg1g2(
        const int4* __restrict__ cfW1, const int* __restrict__ nidx,
        const float* __restrict__ dis, const int* __restrict__ offs,
        const int2* __restrict__ csr, const float4* __restrict__ b1f4,
        const _Float16* __restrict__ W2T, __half* __restrict__ xw2h) {
    __shared__ _Float16 h1s[16 * 264];   // 8.25 KB
    int wave = threadIdx.x >> 6;
    int lane = threadIdx.x & 63;
    int g    = lane >> 5;        // which edge of the pair
    int sl   = lane & 31;        // int4 slot within the 256-half row
    int rowbase = blockIdx.x * 16;

    float4 bb0 = b1f4[2 * sl];
    float4 bb1 = b1f4[2 * sl + 1];

    for (int j = 0; j < 4; ++j) {
        int c = rowbase + wave * 4 + j;
        float d = dis[c];
        int4 sp = cfW1[(size_t)nidx[c] * 32 + sl];
        float esum[8] = {0.f, 0.f, 0.f, 0.f, 0.f, 0.f, 0.f, 0.f};
        int a0 = offs[c], a1 = offs[c + 1];
        int s = a0;
        if (s < a1 && (s & 1)) {
            int sb = __builtin_amdgcn_readfirstlane(s);
            int2 e0 = csr[sb];
            int4 v0 = cfW1[(size_t)(e0.x & 1023) * 32 + sl];
            float n = (g == 0) ? __int_as_float(e0.y) : 0.0f;
            acc8(esum, v0, n);
            ++s;
        }
        for (; s + 8 <= a1; s += 8) {
            int sb = __builtin_amdgcn_readfirstlane(s);
            int4 ee[4];
            #pragma unroll
            for (int u = 0; u < 4; ++u) ee[u] = *(const int4*)(csr + sb + 2 * u);
            int4 v[4]; float n[4];
            #pragma unroll
            for (int u = 0; u < 4; ++u) {
                int ex = g ? ee[u].z : ee[u].x;
                int ey = g ? ee[u].w : ee[u].y;
                n[u] = __int_as_float(ey);
                v[u] = cfW1[(size_t)(ex & 1023) * 32 + sl];
            }
            #pragma unroll
            for (int u = 0; u < 4; ++u) acc8(esum, v[u], n[u]);
        }
        for (; s + 2 <= a1; s += 2) {
            int sb = __builtin_amdgcn_readfirstlane(s);
            int4 ee = *(const int4*)(csr + sb);
            int ex = g ? ee.z : ee.x;
            int ey = g ? ee.w : ee.y;
            int4 v0 = cfW1[(size_t)(ex & 1023) * 32 + sl];
            acc8(esum, v0, __int_as_float(ey));
        }
        if (s < a1) {
            int sb = __builtin_amdgcn_readfirstlane(s);
            int2 e0 = csr[sb];
            int4 v0 = cfW1[(size_t)(e0.x & 1023) * 32 + sl];
            float n = (g == 0) ? __int_as_float(e0.y) : 0.0f;
            acc8(esum, v0, n);
        }
        #pragma unroll
        for (int k = 0; k < 8; ++k) esum[k] += __shfl_xor(esum[k], 32, 64);

        float dd = d * d;
        float2 s0 = __half22float2(*(__half2*)&sp.x);
        float2 s1 = __half22float2(*(__half2*)&sp.y);
        float2 s2 = __half22float2(*(__half2*)&sp.z);
        float2 s3 = __half22float2(*(__half2*)&sp.w);
        float r[8];
        r[0] = bb0.x + s0.x * dd + d * esum[0];
        r[1] = bb0.y + s0.y * dd + d * esum[1];
        r[2] = bb0.z + s1.x * dd + d * esum[2];
        r[3] = bb0.w + s1.y * dd + d * esum[3];
        r[4] = bb1.x + s2.x * dd + d * esum[4];
        r[5] = bb1.y + s2.y * dd + d * esum[5];
        r[6] = bb1.z + s3.x * dd + d * esum[6];
        r[7] = bb1.w + s3.y * dd + d * esum[7];
        #pragma unroll
        for (int k = 0; k < 8; ++k) r[k] = r[k] > 0.f ? r[k] : 0.f;
        float2 p0 = {r[0], r[1]}, p1 = {r[2], r[3]}, p2 = {r[4], r[5]}, p3 = {r[6], r[7]};
        __half2 h0 = __float22half2_rn(p0);
        __half2 h1v = __float22half2_rn(p1);
        __half2 h2 = __float22half2_rn(p2);
        __half2 h3 = __float22half2_rn(p3);
        int4 outv;
        outv.x = *(int*)&h0;
        outv.y = *(int*)&h1v;
        outv.z = *(int*)&h2;
        outv.w = *(int*)&h3;
        if (lane < 32)
            *(int4*)&h1s[(wave * 4 + j) * 264 + sl * 8] = outv;
    }
    __syncthreads();

    int quad = lane >> 4;
    int n    = lane & 15;
    half8 a[8];
    #pragma unroll
    for (int kt = 0; kt < 8; ++kt)
        a[kt] = *(const half8*)&h1s[n * 264 + kt * 32 + quad * 8];
    #pragma unroll
    for (int t2 = 0; t2 < 2; ++t2) {
        int nt = wave * 2 + t2;
        floatx4 acc = {0.f, 0.f, 0.f, 0.f};
        const _Float16* brow = W2T + (size_t)(nt * 16 + n) * H_DIM;
        #pragma unroll
        for (int kt = 0; kt < 8; ++kt) {
            half8 b = *(const half8*)(brow + kt * 32 + quad * 8);
            acc = __builtin_amdgcn_mfma_f32_16x16x32_f16(a[kt], b, acc, 0, 0, 0);
        }
        #pragma unroll
        for (int r = 0; r < 4; ++r) {
            int rowi = rowbase + quad * 4 + r;
            xw2h[(size_t)rowi * O_DIM + nt * 16 + n] = __float2half(acc[r]);
        }
    }
}

// ---------------- layer-2: L2-resident sliced scatter-agg + pool ------------
// One block per dst bucket (256 blocks = 1/CU, all co-resident). acc[256][128]
// fp32 in 128 KB LDS, dims XOR-rotated by dst for ~2-way banks. The block
// walks its 4 src-slice segments in order; since all CUs are in the same
// slice window, each 4 MB xw2h slice is L2-resident -> gathers hit L2.
// Edge-parallel: lane = edge, wave = 8-dim slice (16 B gather/lane), ds_add.

__global__ void __launch_bounds__(1024) k_agg2b(
        const __half* __restrict__ xw2h, const float* __restrict__ b2,
        const float* __restrict__ dis, const int* __restrict__ offs2,
        const int2* __restrict__ csr2, const int* __restrict__ batch,
        float* __restrict__ pool) {
    __shared__ float acc[256 * 128];   // 128 KB
    int t = threadIdx.x;
    int b = blockIdx.x;
    for (int i = t; i < 256 * 128; i += 1024) acc[i] = 0.0f;
    __syncthreads();
    int wave = t >> 6;
    int lane = t & 63;
    int dbase = wave * 8;              // this wave's 8 output dims
    for (int p = 0; p < 4; ++p) {
        int s0 = offs2[b * 4 + p];
        int s1 = offs2[b * 4 + p + 1];
        for (int base = s0; base < s1; base += 64) {
            int j = base + lane;
            int jc = j < s1 ? j : s1 - 1;
            int2 rec = csr2[jc];
            unsigned x = (unsigned)rec.x;
            int src = (int)(x >> 8);
            int dst = (int)(x & 255u);
            float n = (j < s1) ? __int_as_float(rec.y) : 0.0f;
            int4 v = *(const int4*)(xw2h + (size_t)src * O_DIM + dbase);
            float2 f0 = __half22float2(*(__half2*)&v.x);
            float2 f1 = __half22float2(*(__half2*)&v.y);
            float2 f2 = __half22float2(*(__half2*)&v.z);
            float2 f3 = __half22float2(*(__half2*)&v.w);
            int rbase = dst << 7;
            int base0 = dbase ^ (dst & 127);   // (dbase+k)^(dst&127) == base0^k
            atomicAdd(&acc[rbase + (base0 ^ 0)], f0.x * n);
            atomicAdd(&acc[rbase + (base0 ^ 1)], f0.y * n);
            atomicAdd(&acc[rbase + (base0 ^ 2)], f1.x * n);
            atomicAdd(&acc[rbase + (base0 ^ 3)], f1.y * n);
            atomicAdd(&acc[rbase + (base0 ^ 4)], f2.x * n);
            atomicAdd(&acc[rbase + (base0 ^ 5)], f2.y * n);
            atomicAdd(&acc[rbase + (base0 ^ 6)], f3.x * n);
            atomicAdd(&acc[rbase + (base0 ^ 7)], f3.y * n);
        }
    }
    __syncthreads();
    // epilogue: finish (bias + d*esum, relu) + segmented pool reduction
    int dim = t & 127;
    int chunk = t >> 7;                // 8 chunks x 32 nodes
    float bb = b2[dim];
    int cg = -1; float a = 0.0f;
    for (int i = 0; i < 32; ++i) {
        int nloc = chunk * 32 + i;
        int c = b * 256 + nloc;
        float d = dis[c];
        float ph = acc[(nloc << 7) + (dim ^ (nloc & 127))];
        float val = bb + d * ph;
        val = val > 0.0f ? val : 0.0f;
        int g = batch[c];
        if (g != cg) {
            if (cg >= 0) atomicAdd(&pool[cg * O_DIM + dim], a);
            cg = g; a = val;
        } else {
            a += val;
        }
    }
    atomicAdd(&pool[cg * O_DIM + dim], a);
}

__global__ void k_final(const float* __restrict__ pool, const float* __restrict__ cnt,
                        float* __restrict__ out) {
    int t = blockIdx.x * blockDim.x + threadIdx.x;
    if (t < N_GRAPH * O_DIM) {
        int g = t / O_DIM;
        out[t] = pool[t] / fmaxf(cnt[g], 1.0f);
    }
}

// ---------------- launch ----------------

extern "C" void kernel_launch(void* const* d_in, const int* in_sizes, int n_in,
                              void* d_out, int out_size, void* d_ws, size_t ws_size,
                              hipStream_t stream) {
    const float* cf   = (const float*)d_in[0];   // [V,128]
    const float* W1   = (const float*)d_in[1];   // [128,256]
    const float* b1   = (const float*)d_in[2];   // [256]
    const float* W2   = (const float*)d_in[3];   // [256,128]
    const float* b2   = (const float*)d_in[4];   // [128]
    const float* ew   = (const float*)d_in[5];   // [E]
    const int*   nidx = (const int*)d_in[6];     // [N]
    const int*   eidx = (const int*)d_in[7];     // [2,E]
    const int*   bidx = (const int*)d_in[8];     // [N]
    float* out = (float*)d_out;

    const int* row = eidx;            // source
    const int* col = eidx + N_EDGES;  // target

    // workspace layout (bytes)
    char* ws = (char*)d_ws;
    size_t off = 0;
    int*   hist  = (int*)  (ws + off); off += (size_t)N_NODES * 4;          // 256K
    int*   hoffs = (int*)  (ws + off); off += (size_t)N_NODES * 4;          // 256K
    int*   bsum  = (int*)  (ws + off); off += 4096;
    float* dis   = (float*)(ws + off); off += (size_t)N_NODES * 4;          // 256K
    int*   offs  = (int*)  (ws + off); off += (size_t)(N_NODES + 16) * 4;   // 256K
    int2*  csr   = (int2*) (ws + off); off += (size_t)N_EDGES * 8;          // 16M
    float* pool  = (float*)(ws + off); off += (size_t)(N_GRAPH * O_DIM + N_GRAPH) * 4;
    __half* cfW1 = (__half*)(ws + off); off += (size_t)V_SIZE * H_DIM * 2;  // 512K
    _Float16* W2T = (_Float16*)(ws + off); off += (size_t)O_DIM * H_DIM * 2; // 64K
    int*   offs2 = (int*)  (ws + off); off += 4352;                          // 1025 ints
    off = (off + 255) & ~(size_t)255;
    int2*  part  = (int2*) (ws + off); off += (size_t)N_EDGES * 8;          // 16M
    int2*  csr2  = (int2*) (ws + off); off += (size_t)CSR2_TOT * 8;         // 17.3M
    __half* xw2h = (__half*)part;    // part dead after k_build2
    float* cntf  = pool + N_GRAPH * O_DIM;

    // 1. init (pool zero + counts + cfW1 + W2T) + histogram + scan
    k_init<<<256, 256, 0, stream>>>(pool, bidx, cntf, cf, W1, cfW1, W2, W2T);
    k_hist<<<NBLK, 256, 0, stream>>>(col, hist);
    k_scan1<<<256, 256, 0, stream>>>(hist, hoffs, bsum);
    k_scan2<<<1, 256, 0, stream>>>(bsum);

    // 2. partition -> build1 (deg/dis/offs/offs2) -> build2 (csr + sliced csr2)
    k_part<<<NBLK, 256, 0, stream>>>(row, col, ew, nidx, hoffs, bsum, part);
    k_build1<<<256, 256, 0, stream>>>(hoffs, bsum, part, dis, offs, offs2);
    k_build2<<<256, 256, 0, stream>>>(hoffs, bsum, part, dis, offs, offs2, csr, csr2);

    // 3. fused layer-1 aggregate + GEMM2 (LDS tile, no h1 round-trip)
    k_agg1g2<<<N_NODES / 16, 256, 0, stream>>>((const int4*)cfW1, nidx, dis, offs, csr,
                                               (const float4*)b1, W2T, xw2h);

    // 4. layer 2: L2-resident sliced scatter-aggregate + relu + pool
    k_agg2b<<<256, 1024, 0, stream>>>(xw2h, b2, dis, offs2, csr2, bidx, pool);

    // 5. final divide
    k_final<<<(N_GRAPH * O_DIM + 255) / 256, 256, 0, stream>>>(pool, cntf, out);
}

// Round 7
// 417.427 us; speedup vs baseline: 4.0933x; 4.0933x over previous
//
#include <hip/hip_runtime.h>
#include <hip/hip_fp16.h>
#include <math.h>

// Problem constants (match reference)
constexpr int N_NODES = 65536;
constexpr int N_EDGES = 2097152;
constexpr int F_IN    = 128;
constexpr int H_DIM   = 256;
constexpr int O_DIM   = 128;
constexpr int N_GRAPH = 256;
constexpr int V_SIZE  = 1000;

// 256 buckets of 256 nodes (bucket = col>>8); 256 edge-blocks of 8192 edges.
constexpr int EPB  = 8192;
constexpr int NBLK = N_EDGES / EPB;   // 256
constexpr float FXP = 16777216.0f;    // 2^24
constexpr int CSR2_TOT = N_EDGES + N_NODES;   // edges + self-loops

typedef _Float16 half8 __attribute__((ext_vector_type(8)));
typedef float floatx4 __attribute__((ext_vector_type(4)));

// ---------------- init: pool=0, graph counts, cfW1 table, W2T fp16 ----------

__global__ void k_init(float* __restrict__ pool, const int* __restrict__ batch,
                       float* __restrict__ cntf, const float* __restrict__ cf,
                       const float* __restrict__ W1, __half* __restrict__ cfW1,
                       const float* __restrict__ W2, _Float16* __restrict__ W2T) {
    __shared__ float xs[8 * F_IN];    // 4 KB
    int i = blockIdx.x * blockDim.x + threadIdx.x;
    if (i < N_GRAPH * O_DIM) pool[i] = 0.0f;
    if (blockIdx.x == 0) {
        // batch_index sorted: per-graph counts via binary search, no atomics
        int g = threadIdx.x;
        int lo = 0, hi = N_NODES;
        while (lo < hi) { int m = (lo + hi) >> 1; if (batch[m] < g) lo = m + 1; else hi = m; }
        int start = lo;
        lo = 0; hi = N_NODES;
        while (lo < hi) { int m = (lo + hi) >> 1; if (batch[m] <= g) lo = m + 1; else hi = m; }
        cntf[g] = (float)(lo - start);
    }
    if (blockIdx.x < V_SIZE / 8) {    // 125 blocks compute the cfW1 table
        int rb = blockIdx.x * 8;
        int t  = threadIdx.x;
        #pragma unroll
        for (int p = 0; p < 4; ++p) {
            int idx = p * 256 + t;
            int r = idx >> 7, k = idx & 127;
            xs[idx] = cf[(size_t)(rb + r) * F_IN + k];
        }
        __syncthreads();
        float acc[8] = {};
        for (int k = 0; k < F_IN; ++k) {
            float w = W1[k * H_DIM + t];
            #pragma unroll
            for (int j = 0; j < 8; ++j) acc[j] += xs[j * F_IN + k] * w;
        }
        #pragma unroll
        for (int j = 0; j < 8; ++j)
            cfW1[(size_t)(rb + j) * H_DIM + t] = __float2half(acc[j]);
    }
    if (blockIdx.x >= 128) {          // 128 blocks: W2T transpose fp32->fp16
        int idx = (blockIdx.x - 128) * 256 + threadIdx.x;   // 0..32767
        int nn = idx >> 8, kk = idx & 255;
        W2T[idx] = (_Float16)W2[kk * O_DIM + nn];
    }
}

// ---------------- stage A: per-block bucket histogram (LDS) ----------------

__global__ void k_hist(const int* __restrict__ col, int* __restrict__ hist) {
    __shared__ int h[256];
    int t = threadIdx.x;
    h[t] = 0;
    __syncthreads();
    int base = blockIdx.x * EPB;
    #pragma unroll
    for (int i = 0; i < EPB / 256; ++i)
        atomicAdd(&h[col[base + i * 256 + t] >> 8], 1);
    __syncthreads();
    hist[t * NBLK + blockIdx.x] = h[t];   // bucket-major for the scan
}

// ---------------- scan (partial per-256-chunk + block sums) ----------------

__global__ void k_scan1(const int* __restrict__ in, int* __restrict__ out,
                        int* __restrict__ bsum) {
    __shared__ int s[256];
    int tid = threadIdx.x;
    int i = blockIdx.x * 256 + tid;
    int v = in[i];
    s[tid] = v;
    __syncthreads();
    for (int d = 1; d < 256; d <<= 1) {
        int t = (tid >= d) ? s[tid - d] : 0;
        __syncthreads();
        s[tid] += t;
        __syncthreads();
    }
    out[i] = s[tid] - v;
    if (tid == 255) bsum[blockIdx.x] = s[255];
}

__global__ void k_scan2(int* __restrict__ bsum) {
    __shared__ int s[256];
    int tid = threadIdx.x;
    int v = bsum[tid];
    s[tid] = v;
    __syncthreads();
    for (int d = 1; d < 256; d <<= 1) {
        int t = (tid >= d) ? s[tid - d] : 0;
        __syncthreads();
        s[tid] += t;
        __syncthreads();
    }
    bsum[tid] = s[tid] - v;
}

// ---------------- stage C: partition into int2 records ----------------------
// rec.x = src:16 | dst8:8 | vocab_hi:8 ; rec.y = vocab_lo:2<<16 | ew_fp16:16

__global__ void k_part(const int* __restrict__ row, const int* __restrict__ col,
                       const float* __restrict__ ew, const int* __restrict__ nidx,
                       const int* __restrict__ hoffs, const int* __restrict__ bsum,
                       int2* __restrict__ part) {
    __shared__ int cur[256];
    int t = threadIdx.x;
    cur[t] = hoffs[t * NBLK + blockIdx.x] + bsum[t];
    __syncthreads();
    int base = blockIdx.x * EPB;
    for (int i = 0; i < EPB / 256; ++i) {
        int e = base + i * 256 + t;
        int r = row[e], c = col[e];
        unsigned hw = (unsigned)__half_as_ushort(__float2half(ew[e]));
        int vb = nidx[r];
        int slot = atomicAdd(&cur[c >> 8], 1);
        int2 rec;
        rec.x = (r << 16) | ((c & 255) << 8) | (vb >> 2);
        rec.y = (int)(((unsigned)(vb & 3) << 16) | hw);
        part[slot] = rec;
    }
}

// ---------------- stage D1: per-bucket deg/dis + offs + (slice,dst) offs3 ---
// offs3[bucket*1024 + p*256 + dst] = start of dst's slice-p run in csr2
// (slice-major, dst-minor, contiguous; self-loop slot counted in home slice).

__global__ void k_build1(const int* __restrict__ hoffs, const int* __restrict__ bsum,
                         const int2* __restrict__ part, float* __restrict__ dis,
                         int* __restrict__ offs, int* __restrict__ offs3) {
    __shared__ unsigned long long dc[256];
    __shared__ int sc[256];
    __shared__ int cnt4[1024];
    int t = threadIdx.x;
    int bucket = blockIdx.x;
    dc[t] = 0ULL;
    for (int i = t; i < 1024; i += 256) cnt4[i] = 0;
    __syncthreads();
    int start = hoffs[bucket * NBLK] + bsum[bucket];
    int end   = (bucket == 255) ? N_EDGES : (hoffs[(bucket + 1) * NBLK] + bsum[bucket + 1]);
    for (int j = start + t; j < end; j += 256) {
        int2 rec = part[j];
        int dst = (rec.x >> 8) & 255;
        float w = __half2float(__ushort_as_half((unsigned short)(rec.y & 0xFFFF)));
        atomicAdd(&dc[dst], (1ULL << 40) |
                  (unsigned long long)(unsigned)(w * FXP + 0.5f));
        int p = (int)(((unsigned)rec.x) >> 30);    // src>>14
        atomicAdd(&cnt4[p * 256 + dst], 1);
    }
    __syncthreads();
    unsigned long long v = dc[t];
    float deg = 1.0f + (float)(v & 0xFFFFFFFFFFULL) * (1.0f / FXP);   // self-loop +1
    dis[bucket * 256 + t] = 1.0f / sqrtf(deg);                        // deg >= 1
    int sb = bucket >> 6;
    cnt4[sb * 256 + t] += 1;          // reserve self-loop slot (distinct idx per t)
    // ---- per-dst scan for offs (agg1 CSR) ----
    int cnt = (int)(v >> 40);
    sc[t] = cnt;
    __syncthreads();
    for (int d = 1; d < 256; d <<= 1) {
        int x = (t >= d) ? sc[t - d] : 0;
        __syncthreads();
        sc[t] += x;
        __syncthreads();
    }
    offs[bucket * 256 + t] = start + sc[t] - cnt;
    if (bucket == 255 && t == 255) offs[N_NODES] = N_EDGES;
    __syncthreads();
    // ---- 1024-wide scan for offs3 (slice-major, dst-minor) ----
    int i0 = 4 * t;
    int a0 = cnt4[i0], a1 = cnt4[i0 + 1], a2 = cnt4[i0 + 2], a3 = cnt4[i0 + 3];
    int tsum = a0 + a1 + a2 + a3;
    __syncthreads();
    sc[t] = tsum;
    __syncthreads();
    for (int d = 1; d < 256; d <<= 1) {
        int x = (t >= d) ? sc[t - d] : 0;
        __syncthreads();
        sc[t] += x;
        __syncthreads();
    }
    int ebase = start + bucket * 256 + (sc[t] - tsum);  // +256 self slots/bucket
    offs3[bucket * 1024 + i0]     = ebase;
    offs3[bucket * 1024 + i0 + 1] = ebase + a0;
    offs3[bucket * 1024 + i0 + 2] = ebase + a0 + a1;
    offs3[bucket * 1024 + i0 + 3] = ebase + a0 + a1 + a2;
    if (bucket == 255 && t == 255) offs3[256 * 1024] = CSR2_TOT;
}

// ---------------- stage D2: scatter to csr (agg1) + run-segmented csr2 ------
// csr : x = src<<10 | vocab ; y = dis[src]*ew     (per-dst, for agg1)
// csr2: x = src ; y = dis[src]*ew                 (per (bucket,slice,dst) run)
// self-loop record (src=c, nrm=dis[c]) at the front of c's home-slice run.

__global__ void k_build2(const int* __restrict__ hoffs, const int* __restrict__ bsum,
                         const int2* __restrict__ part, const float* __restrict__ dis,
                         const int* __restrict__ offs, const int* __restrict__ offs3,
                         int2* __restrict__ csr, int2* __restrict__ csr2) {
    __shared__ int cur[256];
    __shared__ int cur3[1024];
    int t = threadIdx.x;
    int bucket = blockIdx.x;
    int sb = bucket >> 6;
    cur[t] = offs[bucket * 256 + t];
    for (int i = t; i < 1024; i += 256) cur3[i] = offs3[bucket * 1024 + i];
    __syncthreads();
    // self-loop record for node bucket*256+t (each thread owns one cur3 entry)
    {
        int c = bucket * 256 + t;
        int pos = cur3[sb * 256 + t];
        int2 r2;
        r2.x = c;
        r2.y = __float_as_int(dis[c]);
        csr2[pos] = r2;
        cur3[sb * 256 + t] = pos + 1;
    }
    __syncthreads();
    int start = hoffs[bucket * NBLK] + bsum[bucket];
    int end   = (bucket == 255) ? N_EDGES : (hoffs[(bucket + 1) * NBLK] + bsum[bucket + 1]);
    for (int j = start + t; j < end; j += 256) {
        int2 rec = part[j];
        int dst = (rec.x >> 8) & 255;
        unsigned src = ((unsigned)rec.x) >> 16;
        int vb = ((rec.x & 255) << 2) | ((rec.y >> 16) & 3);
        float w = __half2float(__ushort_as_half((unsigned short)(rec.y & 0xFFFF)));
        float nm = dis[src] * w;
        int slot = atomicAdd(&cur[dst], 1);
        int2 e;
        e.x = (int)((src << 10) | (unsigned)vb);
        e.y = __float_as_int(nm);
        csr[slot] = e;
        int p = (int)(src >> 14);
        int slot2 = atomicAdd(&cur3[p * 256 + dst], 1);
        int2 r2;
        r2.x = (int)src;
        r2.y = __float_as_int(nm);
        csr2[slot2] = r2;
    }
}

// 8-half fp16 row-fragment accumulate: e[k] += f32(v[k]) * n
__device__ __forceinline__ void acc8(float* e, int4 v, float n) {
    float2 f0 = __half22float2(*(__half2*)&v.x);
    float2 f1 = __half22float2(*(__half2*)&v.y);
    float2 f2 = __half22float2(*(__half2*)&v.z);
    float2 f3 = __half22float2(*(__half2*)&v.w);
    e[0] += f0.x * n; e[1] += f0.y * n;
    e[2] += f1.x * n; e[3] += f1.y * n;
    e[4] += f2.x * n; e[5] += f2.y * n;
    e[6] += f3.x * n; e[7] += f3.y * n;
}

// ---------------- fused layer-1 agg + GEMM2 (unchanged) ---------------------

__global__ void __launch_bounds__(256) k_agg1g2(
        const int4* __restrict__ cfW1, const int* __restrict__ nidx,
        const float* __restrict__ dis, const int* __restrict__ offs,
        const int2* __restrict__ csr, const float4* __restrict__ b1f4,
        const _Float16* __restrict__ W2T, __half* __restrict__ xw2h) {
    __shared__ _Float16 h1s[16 * 264];   // 8.25 KB
    int wave = threadIdx.x >> 6;
    int lane = threadIdx.x & 63;
    int g    = lane >> 5;        // which edge of the pair
    int sl   = lane & 31;        // int4 slot within the 256-half row
    int rowbase = blockIdx.x * 16;

    float4 bb0 = b1f4[2 * sl];
    float4 bb1 = b1f4[2 * sl + 1];

    for (int j = 0; j < 4; ++j) {
        int c = rowbase + wave * 4 + j;
        float d = dis[c];
        int4 sp = cfW1[(size_t)nidx[c] * 32 + sl];
        float esum[8] = {0.f, 0.f, 0.f, 0.f, 0.f, 0.f, 0.f, 0.f};
        int a0 = offs[c], a1 = offs[c + 1];
        int s = a0;
        if (s < a1 && (s & 1)) {
            int sb = __builtin_amdgcn_readfirstlane(s);
            int2 e0 = csr[sb];
            int4 v0 = cfW1[(size_t)(e0.x & 1023) * 32 + sl];
            float n = (g == 0) ? __int_as_float(e0.y) : 0.0f;
            acc8(esum, v0, n);
            ++s;
        }
        for (; s + 8 <= a1; s += 8) {
            int sb = __builtin_amdgcn_readfirstlane(s);
            int4 ee[4];
            #pragma unroll
            for (int u = 0; u < 4; ++u) ee[u] = *(const int4*)(csr + sb + 2 * u);
            int4 v[4]; float n[4];
            #pragma unroll
            for (int u = 0; u < 4; ++u) {
                int ex = g ? ee[u].z : ee[u].x;
                int ey = g ? ee[u].w : ee[u].y;
                n[u] = __int_as_float(ey);
                v[u] = cfW1[(size_t)(ex & 1023) * 32 + sl];
            }
            #pragma unroll
            for (int u = 0; u < 4; ++u) acc8(esum, v[u], n[u]);
        }
        for (; s + 2 <= a1; s += 2) {
            int sb = __builtin_amdgcn_readfirstlane(s);
            int4 ee = *(const int4*)(csr + sb);
            int ex = g ? ee.z : ee.x;
            int ey = g ? ee.w : ee.y;
            int4 v0 = cfW1[(size_t)(ex & 1023) * 32 + sl];
            acc8(esum, v0, __int_as_float(ey));
        }
        if (s < a1) {
            int sb = __builtin_amdgcn_readfirstlane(s);
            int2 e0 = csr[sb];
            int4 v0 = cfW1[(size_t)(e0.x & 1023) * 32 + sl];
            float n = (g == 0) ? __int_as_float(e0.y) : 0.0f;
            acc8(esum, v0, n);
        }
        #pragma unroll
        for (int k = 0; k < 8; ++k) esum[k] += __shfl_xor(esum[k], 32, 64);

        float dd = d * d;
        float2 s0 = __half22float2(*(__half2*)&sp.x);
        float2 s1 = __half22float2(*(__half2*)&sp.y);
        float2 s2 = __half22float2(*(__half2*)&sp.z);
        float2 s3 = __half22float2(*(__half2*)&sp.w);
        float r[8];
        r[0] = bb0.x + s0.x * dd + d * esum[0];
        r[1] = bb0.y + s0.y * dd + d * esum[1];
        r[2] = bb0.z + s1.x * dd + d * esum[2];
        r[3] = bb0.w + s1.y * dd + d * esum[3];
        r[4] = bb1.x + s2.x * dd + d * esum[4];
        r[5] = bb1.y + s2.y * dd + d * esum[5];
        r[6] = bb1.z + s3.x * dd + d * esum[6];
        r[7] = bb1.w + s3.y * dd + d * esum[7];
        #pragma unroll
        for (int k = 0; k < 8; ++k) r[k] = r[k] > 0.f ? r[k] : 0.f;
        float2 p0 = {r[0], r[1]}, p1 = {r[2], r[3]}, p2 = {r[4], r[5]}, p3 = {r[6], r[7]};
        __half2 h0 = __float22half2_rn(p0);
        __half2 h1v = __float22half2_rn(p1);
        __half2 h2 = __float22half2_rn(p2);
        __half2 h3 = __float22half2_rn(p3);
        int4 outv;
        outv.x = *(int*)&h0;
        outv.y = *(int*)&h1v;
        outv.z = *(int*)&h2;
        outv.w = *(int*)&h3;
        if (lane < 32)
            *(int4*)&h1s[(wave * 4 + j) * 264 + sl * 8] = outv;
    }
    __syncthreads();

    int quad = lane >> 4;
    int n    = lane & 15;
    half8 a[8];
    #pragma unroll
    for (int kt = 0; kt < 8; ++kt)
        a[kt] = *(const half8*)&h1s[n * 264 + kt * 32 + quad * 8];
    #pragma unroll
    for (int t2 = 0; t2 < 2; ++t2) {
        int nt = wave * 2 + t2;
        floatx4 acc = {0.f, 0.f, 0.f, 0.f};
        const _Float16* brow = W2T + (size_t)(nt * 16 + n) * H_DIM;
        #pragma unroll
        for (int kt = 0; kt < 8; ++kt) {
            half8 b = *(const half8*)(brow + kt * 32 + quad * 8);
            acc = __builtin_amdgcn_mfma_f32_16x16x32_f16(a[kt], b, acc, 0, 0, 0);
        }
        #pragma unroll
        for (int r = 0; r < 4; ++r) {
            int rowi = rowbase + quad * 4 + r;
            xw2h[(size_t)rowi * O_DIM + nt * 16 + n] = __float2half(acc[r]);
        }
    }
}

// ---------------- layer-2: slice-ordered gather-agg + relu + pool -----------
// 2048 blocks x 256 thr, ALL co-resident (16 waves/CU). Wave owns 8 dst nodes
// and walks their 4 src-slice runs in slice order; every CU sweeps slice p in
// the same window, so each XCD's 4 MB L2 holds exactly one 4 MB xw2h slice.
// Owner-computes gather (4 edges/gather-instr via grp=lane>>4, NO atomics in
// the hot loop). Self-loops are csr2 records. Register-segmented pool.

__global__ void __launch_bounds__(256) k_agg2c(
        const int4* __restrict__ xw2h, const float* __restrict__ b2,
        const float* __restrict__ dis, const int* __restrict__ offs3,
        const int2* __restrict__ csr2, const int* __restrict__ batch,
        float* __restrict__ pool) {
    int t = threadIdx.x;
    int wave = t >> 6, lane = t & 63;
    int grp = lane >> 4, sl = lane & 15;
    int n0 = blockIdx.x * 32 + wave * 8;     // 8 nodes per wave, same bucket
    int bucket = n0 >> 8;
    float4 bb0 = ((const float4*)b2)[2 * sl];
    float4 bb1 = ((const float4*)b2)[2 * sl + 1];
    float gsum[8] = {0.f, 0.f, 0.f, 0.f, 0.f, 0.f, 0.f, 0.f};
    int cg = batch[n0];
    for (int j = 0; j < 8; ++j) {
        int c = n0 + j;
        float esum[8] = {0.f, 0.f, 0.f, 0.f, 0.f, 0.f, 0.f, 0.f};
        #pragma unroll
        for (int p = 0; p < 4; ++p) {
            int idx = bucket * 1024 + p * 256 + (c & 255);
            int s  = offs3[idx];
            int e1 = offs3[idx + 1];
            for (; s + 8 <= e1; s += 8) {
                int sb_ = __builtin_amdgcn_readfirstlane(s);
                int2 ea = csr2[sb_ + grp];
                int2 eb = csr2[sb_ + 4 + grp];
                int4 va = xw2h[(size_t)ea.x * 16 + sl];
                int4 vb = xw2h[(size_t)eb.x * 16 + sl];
                acc8(esum, va, __int_as_float(ea.y));
                acc8(esum, vb, __int_as_float(eb.y));
            }
            if (s < e1) {
                int sb_ = __builtin_amdgcn_readfirstlane(s);
                int i1 = sb_ + grp;
                int ic = i1 < e1 ? i1 : e1 - 1;
                int2 ea = csr2[ic];
                int4 va = xw2h[(size_t)ea.x * 16 + sl];
                acc8(esum, va, (i1 < e1) ? __int_as_float(ea.y) : 0.0f);
                if (sb_ + 4 < e1) {
                    int i2 = sb_ + 4 + grp;
                    int ic2 = i2 < e1 ? i2 : e1 - 1;
                    int2 eb = csr2[ic2];
                    int4 vb = xw2h[(size_t)eb.x * 16 + sl];
                    acc8(esum, vb, (i2 < e1) ? __int_as_float(eb.y) : 0.0f);
                }
            }
        }
        #pragma unroll
        for (int k = 0; k < 8; ++k) {
            esum[k] += __shfl_xor(esum[k], 16, 64);
            esum[k] += __shfl_xor(esum[k], 32, 64);
        }
        float d = dis[c];
        float a[8];
        a[0] = bb0.x + d * esum[0]; a[1] = bb0.y + d * esum[1];
        a[2] = bb0.z + d * esum[2]; a[3] = bb0.w + d * esum[3];
        a[4] = bb1.x + d * esum[4]; a[5] = bb1.y + d * esum[5];
        a[6] = bb1.z + d * esum[6]; a[7] = bb1.w + d * esum[7];
        #pragma unroll
        for (int k = 0; k < 8; ++k) a[k] = a[k] > 0.f ? a[k] : 0.f;
        int g = batch[c];
        if (g != cg) {
            if (grp == 0) {
                #pragma unroll
                for (int k = 0; k < 8; ++k)
                    atomicAdd(&pool[cg * O_DIM + sl * 8 + k], gsum[k]);
            }
            cg = g;
            #pragma unroll
            for (int k = 0; k < 8; ++k) gsum[k] = a[k];
        } else {
            #pragma unroll
            for (int k = 0; k < 8; ++k) gsum[k] += a[k];
        }
    }
    if (grp == 0) {
        #pragma unroll
        for (int k = 0; k < 8; ++k)
            atomicAdd(&pool[cg * O_DIM + sl * 8 + k], gsum[k]);
    }
}

__global__ void k_final(const float* __restrict__ pool, const float* __restrict__ cnt,
                        float* __restrict__ out) {
    int t = blockIdx.x * blockDim.x + threadIdx.x;
    if (t < N_GRAPH * O_DIM) {
        int g = t / O_DIM;
        out[t] = pool[t] / fmaxf(cnt[g], 1.0f);
    }
}

// ---------------- launch ----------------

extern "C" void kernel_launch(void* const* d_in, const int* in_sizes, int n_in,
                              void* d_out, int out_size, void* d_ws, size_t ws_size,
                              hipStream_t stream) {
    const float* cf   = (const float*)d_in[0];   // [V,128]
    const float* W1   = (const float*)d_in[1];   // [128,256]
    const float* b1   = (const float*)d_in[2];   // [256]
    const float* W2   = (const float*)d_in[3];   // [256,128]
    const float* b2   = (const float*)d_in[4];   // [128]
    const float* ew   = (const float*)d_in[5];   // [E]
    const int*   nidx = (const int*)d_in[6];     // [N]
    const int*   eidx = (const int*)d_in[7];     // [2,E]
    const int*   bidx = (const int*)d_in[8];     // [N]
    float* out = (float*)d_out;

    const int* row = eidx;            // source
    const int* col = eidx + N_EDGES;  // target

    // workspace layout (bytes)
    char* ws = (char*)d_ws;
    size_t off = 0;
    int*   hist  = (int*)  (ws + off); off += (size_t)N_NODES * 4;          // 256K
    int*   hoffs = (int*)  (ws + off); off += (size_t)N_NODES * 4;          // 256K
    int*   bsum  = (int*)  (ws + off); off += 4096;
    float* dis   = (float*)(ws + off); off += (size_t)N_NODES * 4;          // 256K
    int*   offs  = (int*)  (ws + off); off += (size_t)(N_NODES + 16) * 4;   // 256K
    int2*  csr   = (int2*) (ws + off); off += (size_t)N_EDGES * 8;          // 16M
    float* pool  = (float*)(ws + off); off += (size_t)(N_GRAPH * O_DIM + N_GRAPH) * 4;
    __half* cfW1 = (__half*)(ws + off); off += (size_t)V_SIZE * H_DIM * 2;  // 512K
    _Float16* W2T = (_Float16*)(ws + off); off += (size_t)O_DIM * H_DIM * 2; // 64K
    int*   offs3 = (int*)  (ws + off); off += (size_t)(256 * 1024 + 16) * 4; // 1M
    off = (off + 255) & ~(size_t)255;
    int2*  part  = (int2*) (ws + off); off += (size_t)N_EDGES * 8;          // 16M
    int2*  csr2  = (int2*) (ws + off); off += (size_t)CSR2_TOT * 8;         // 17.3M
    __half* xw2h = (__half*)part;    // part dead after k_build2
    float* cntf  = pool + N_GRAPH * O_DIM;

    // 1. init (pool zero + counts + cfW1 + W2T) + histogram + scan
    k_init<<<256, 256, 0, stream>>>(pool, bidx, cntf, cf, W1, cfW1, W2, W2T);
    k_hist<<<NBLK, 256, 0, stream>>>(col, hist);
    k_scan1<<<256, 256, 0, stream>>>(hist, hoffs, bsum);
    k_scan2<<<1, 256, 0, stream>>>(bsum);

    // 2. partition -> build1 (deg/dis/offs/offs3) -> build2 (csr + run csr2)
    k_part<<<NBLK, 256, 0, stream>>>(row, col, ew, nidx, hoffs, bsum, part);
    k_build1<<<256, 256, 0, stream>>>(hoffs, bsum, part, dis, offs, offs3);
    k_build2<<<256, 256, 0, stream>>>(hoffs, bsum, part, dis, offs, offs3, csr, csr2);

    // 3. fused layer-1 aggregate + GEMM2 (LDS tile, no h1 round-trip)
    k_agg1g2<<<N_NODES / 16, 256, 0, stream>>>((const int4*)cfW1, nidx, dis, offs, csr,
                                               (const float4*)b1, W2T, xw2h);

    // 4. layer 2: slice-ordered gather-aggregate + relu + pool (no atomic agg)
    k_agg2c<<<N_NODES / 32, 256, 0, stream>>>((const int4*)xw2h, b2, dis, offs3,
                                              csr2, bidx, pool);

    // 5. final divide
    k_final<<<(N_GRAPH * O_DIM + 255) / 256, 256, 0, stream>>>(pool, cntf, out);
}